// Round 1
// baseline (7370.008 us; speedup 1.0000x reference)
//
#include <hip/hip_runtime.h>

// Transformer forward, MI355X gfx950.
// B=2 T=1024 V=2048 D=1024 H=16 DK=64 L=8. All inputs fp32; compute in bf16 MFMA
// with fp32 accumulation; residual stream kept fp32.

typedef __attribute__((ext_vector_type(8))) short v8s;   // 8 bf16 in 4 VGPRs (MFMA A/B frag)
typedef __attribute__((ext_vector_type(4))) float v4f;   // MFMA C/D frag

#define DEV static __device__ __forceinline__

DEV float b2f(unsigned short u) { return __uint_as_float(((unsigned)u) << 16); }
DEV unsigned short f2bf(float f) {            // round-to-nearest-even fp32->bf16
  unsigned u = __float_as_uint(f);
  u += 0x7fff + ((u >> 16) & 1);
  return (unsigned short)(u >> 16);
}

// ---------------------------------------------------------------- fp32 -> bf16 bulk convert
__global__ __launch_bounds__(256) void f2b_kernel(const float* __restrict__ in,
                                                  unsigned short* __restrict__ out, int n8) {
  int i = blockIdx.x * 256 + threadIdx.x;
  if (i >= n8) return;
  const float4* ip = (const float4*)in;
  float4 a = ip[2 * i], b = ip[2 * i + 1];
  uint4 u;
  u.x = (unsigned)f2bf(a.x) | ((unsigned)f2bf(a.y) << 16);
  u.y = (unsigned)f2bf(a.z) | ((unsigned)f2bf(a.w) << 16);
  u.z = (unsigned)f2bf(b.x) | ((unsigned)f2bf(b.y) << 16);
  u.w = (unsigned)f2bf(b.z) | ((unsigned)f2bf(b.w) << 16);
  ((uint4*)out)[i] = u;
}

// ---------------------------------------------------------------- transpose+convert pack
// out[c][r] (bf16, row stride out_rs) = in[r][c] (fp32, row stride in_rs); 32x32 LDS tiles.
// grid: (C/32, R/32, Z) with per-z base offsets. block (32,8).
__global__ __launch_bounds__(256) void tpack_kernel(const float* __restrict__ in,
                                                    unsigned short* __restrict__ out,
                                                    int in_rs, int out_rs, long in_zs, long out_zs) {
  __shared__ float tl[32][33];
  const float* ip = in + (long)blockIdx.z * in_zs;
  unsigned short* op = out + (long)blockIdx.z * out_zs;
  int c0 = blockIdx.x * 32, r0 = blockIdx.y * 32;
  int tx = threadIdx.x, ty = threadIdx.y;
#pragma unroll
  for (int i = 0; i < 4; i++) {
    int r = ty + i * 8;
    tl[r][tx] = ip[(long)(r0 + r) * in_rs + c0 + tx];
  }
  __syncthreads();
#pragma unroll
  for (int i = 0; i < 4; i++) {
    int cr = ty + i * 8;
    op[(long)(c0 + cr) * out_rs + r0 + tx] = f2bf(tl[tx][cr]);
  }
}

// ---------------------------------------------------------------- LayerNorm (fp32 in, bf16 out)
// one block per row, D=1024, 256 threads x float4
__global__ __launch_bounds__(256) void ln_kernel(const float* __restrict__ x,
                                                 const float* __restrict__ g,
                                                 const float* __restrict__ b,
                                                 unsigned short* __restrict__ out) {
  int row = blockIdx.x, t = threadIdx.x;
  const float4* xr = (const float4*)(x + (long)row * 1024);
  float4 v = xr[t];
  float s = v.x + v.y + v.z + v.w;
  float ss = v.x * v.x + v.y * v.y + v.z * v.z + v.w * v.w;
#pragma unroll
  for (int o = 32; o > 0; o >>= 1) { s += __shfl_xor(s, o); ss += __shfl_xor(ss, o); }
  __shared__ float ps[4], pss[4];
  int wid = t >> 6;
  if ((t & 63) == 0) { ps[wid] = s; pss[wid] = ss; }
  __syncthreads();
  s = ps[0] + ps[1] + ps[2] + ps[3];
  ss = pss[0] + pss[1] + pss[2] + pss[3];
  float mean = s * (1.0f / 1024.0f);
  float var = ss * (1.0f / 1024.0f) - mean * mean;
  float rstd = rsqrtf(var + 1e-5f);
  float4 gg = ((const float4*)g)[t];
  float4 bb = ((const float4*)b)[t];
  unsigned o0 = f2bf((v.x - mean) * rstd * gg.x + bb.x);
  unsigned o1 = f2bf((v.y - mean) * rstd * gg.y + bb.y);
  unsigned o2 = f2bf((v.z - mean) * rstd * gg.z + bb.z);
  unsigned o3 = f2bf((v.w - mean) * rstd * gg.w + bb.w);
  uint2 u; u.x = o0 | (o1 << 16); u.y = o2 | (o3 << 16);
  ((uint2*)(out + (long)row * 1024))[t] = u;
}

// ---------------------------------------------------------------- bf16 MFMA GEMM, B transposed
// C[M,N] = A[M,K] * Bt[N,K]^T (+epilogue). Tile: BM = MT*32 (MT=4 ->128, MT=2 ->64), BN=128, BK=64.
// 256 threads = 4 waves in 2x2; each wave: (MT x 4) grid of 16x16x32 MFMAs.
// modes: 0=embed(+tok_b+pos_emb -> f32 x) 1=qkv(+b -> bf16) 2=ff1(+b,relu -> bf16)
//        3=resid(x += acc+b, f32)         4=head(+b -> f32 out)
template <int MT>
__global__ __launch_bounds__(256) void gemm_bt(const unsigned short* __restrict__ A,
                                               const unsigned short* __restrict__ Bt,
                                               int M, int N, int K, int mode,
                                               const float* __restrict__ bias0,
                                               const float* __restrict__ bias1,
                                               const float* __restrict__ bias2,
                                               const float* __restrict__ posemb,
                                               float* __restrict__ fout,
                                               unsigned short* __restrict__ bout) {
  __shared__ unsigned short As[MT * 32 * 72];  // +8 bf16 pad per 64-wide row: stride 144B
  __shared__ unsigned short Bs[128 * 72];
  int tid = threadIdx.x;
  int lane = tid & 63, wid = tid >> 6;
  int wm = (wid >> 1) * MT * 16, wn = (wid & 1) * 64;
  int ln15 = lane & 15, q8 = (lane >> 4) * 8;
  int row0 = blockIdx.y * (MT * 32), n0 = blockIdx.x * 128;

  int rs = tid >> 3, cs = (tid & 7) * 8;
  const unsigned short* Ap[MT]; const unsigned short* Bp[4];
  unsigned short* Al[MT]; unsigned short* Bl[4];
#pragma unroll
  for (int j = 0; j < MT; j++) {
    int r = j * 32 + rs;
    Ap[j] = A + (long)(row0 + r) * K + cs;
    Al[j] = &As[r * 72 + cs];
  }
#pragma unroll
  for (int j = 0; j < 4; j++) {
    int r = j * 32 + rs;
    Bp[j] = Bt + (long)(n0 + r) * K + cs;
    Bl[j] = &Bs[r * 72 + cs];
  }

  v4f acc[MT][4];
  v4f zero = {0.f, 0.f, 0.f, 0.f};
#pragma unroll
  for (int m = 0; m < MT; m++)
#pragma unroll
    for (int n = 0; n < 4; n++) acc[m][n] = zero;

  for (int k0 = 0; k0 < K; k0 += 64) {
    if (k0) __syncthreads();
#pragma unroll
    for (int j = 0; j < MT; j++) { uint4 ua = *(const uint4*)(Ap[j] + k0); *(uint4*)Al[j] = ua; }
#pragma unroll
    for (int j = 0; j < 4; j++) { uint4 ub = *(const uint4*)(Bp[j] + k0); *(uint4*)Bl[j] = ub; }
    __syncthreads();
#pragma unroll
    for (int ks = 0; ks < 2; ks++) {
      int ko = ks * 32 + q8;
      v8s af[MT], bfv[4];
#pragma unroll
      for (int m = 0; m < MT; m++) af[m] = *(const v8s*)&As[(wm + m * 16 + ln15) * 72 + ko];
#pragma unroll
      for (int n = 0; n < 4; n++) bfv[n] = *(const v8s*)&Bs[(wn + n * 16 + ln15) * 72 + ko];
#pragma unroll
      for (int m = 0; m < MT; m++)
#pragma unroll
        for (int n = 0; n < 4; n++)
          acc[m][n] = __builtin_amdgcn_mfma_f32_16x16x32_bf16(af[m], bfv[n], acc[m][n], 0, 0, 0);
    }
  }

  // epilogue: C/D layout col = lane&15, row = (lane>>4)*4 + reg
  int q4 = (lane >> 4) * 4;
#pragma unroll
  for (int m = 0; m < MT; m++) {
#pragma unroll
    for (int n = 0; n < 4; n++) {
      int gn = n0 + wn + n * 16 + ln15;
      float bcol;
      if (mode == 1)
        bcol = gn < 1024 ? bias0[gn] : (gn < 2048 ? bias1[gn - 1024] : bias2[gn - 2048]);
      else
        bcol = bias0[gn];
#pragma unroll
      for (int r = 0; r < 4; r++) {
        int gm = row0 + wm + m * 16 + q4 + r;
        float v = acc[m][n][r] + bcol;
        if (mode == 0) {
          fout[(long)gm * N + gn] = v + posemb[(long)(gm & 1023) * 1024 + gn];
        } else if (mode == 1) {
          bout[(long)gm * N + gn] = f2bf(v);
        } else if (mode == 2) {
          bout[(long)gm * N + gn] = f2bf(fmaxf(v, 0.f));
        } else if (mode == 3) {
          fout[(long)gm * N + gn] += v;
        } else {
          fout[(long)gm * N + gn] = v;
        }
      }
    }
  }
}

// ---------------------------------------------------------------- causal attention
// qkv: [B*T, 3072] bf16, cols [0,1024)=Q [1024,2048)=K [2048,3072)=V, each h-major (h*64+dk).
// one wave per (b,h,t). Y: [B*T, 1024] bf16 h-major.
__global__ __launch_bounds__(256) void attn_kernel(const unsigned short* __restrict__ qkv,
                                                   unsigned short* __restrict__ Y) {
  __shared__ float sc[4][1024];
  __shared__ float qs[4][64];
  int tid = threadIdx.x, wid = tid >> 6, lane = tid & 63;
  int w = blockIdx.x * 4 + wid;     // [0, 32768)
  int t = w & 1023, h = (w >> 10) & 15, b = w >> 14;
  long rowq = ((long)(b * 1024 + t)) * 3072 + h * 64;
  qs[wid][lane] = b2f(qkv[rowq + lane]);
  __syncthreads();
  float qr[64];
#pragma unroll
  for (int j = 0; j < 64; j++) qr[j] = qs[wid][j];

  const unsigned short* kbase = qkv + (long)b * 1024 * 3072 + 1024 + h * 64;
  int smax = (t + 64) & ~63;
  float lmax = -INFINITY;
  for (int s = lane; s <= t; s += 64) {
    const uint4* kp = (const uint4*)(kbase + (long)s * 3072);
    float acc = 0.f;
#pragma unroll
    for (int c = 0; c < 8; c++) {
      uint4 u = kp[c];
      acc += qr[c * 8 + 0] * b2f((unsigned short)(u.x & 0xffff));
      acc += qr[c * 8 + 1] * b2f((unsigned short)(u.x >> 16));
      acc += qr[c * 8 + 2] * b2f((unsigned short)(u.y & 0xffff));
      acc += qr[c * 8 + 3] * b2f((unsigned short)(u.y >> 16));
      acc += qr[c * 8 + 4] * b2f((unsigned short)(u.z & 0xffff));
      acc += qr[c * 8 + 5] * b2f((unsigned short)(u.z >> 16));
      acc += qr[c * 8 + 6] * b2f((unsigned short)(u.w & 0xffff));
      acc += qr[c * 8 + 7] * b2f((unsigned short)(u.w >> 16));
    }
    float sv = acc * 0.125f;       // DK^-0.5
    sc[wid][s] = sv;
    lmax = fmaxf(lmax, sv);
  }
#pragma unroll
  for (int o = 32; o > 0; o >>= 1) lmax = fmaxf(lmax, __shfl_xor(lmax, o));
  float lsum = 0.f;
  for (int s = lane; s < smax; s += 64) {
    float p = 0.f;
    if (s <= t) p = __expf(sc[wid][s] - lmax);
    sc[wid][s] = p;
    lsum += p;
  }
#pragma unroll
  for (int o = 32; o > 0; o >>= 1) lsum += __shfl_xor(lsum, o);
  float inv = 1.0f / lsum;
  __syncthreads();
  const unsigned short* vbase = qkv + (long)b * 1024 * 3072 + 2048 + h * 64 + lane;
  const float4* sp = (const float4*)sc[wid];
  float o = 0.f;
  for (int s4 = 0; s4 < (smax >> 2); s4++) {
    float4 p = sp[s4];
    int s = s4 * 4;
    o += p.x * b2f(vbase[(long)(s + 0) * 3072]);
    o += p.y * b2f(vbase[(long)(s + 1) * 3072]);
    o += p.z * b2f(vbase[(long)(s + 2) * 3072]);
    o += p.w * b2f(vbase[(long)(s + 3) * 3072]);
  }
  Y[((long)(b * 1024 + t)) * 1024 + h * 64 + lane] = f2bf(o * inv);
}

// ---------------------------------------------------------------- host
extern "C" void kernel_launch(void* const* d_in, const int* in_sizes, int n_in,
                              void* d_out, int out_size, void* d_ws, size_t ws_size,
                              hipStream_t stream) {
  const float* idx   = (const float*)d_in[0];
  const float* tok_w = (const float*)d_in[1];
  const float* tok_b = (const float*)d_in[2];
  const float* pos   = (const float*)d_in[3];
  const float* ln1g  = (const float*)d_in[4];
  const float* ln1b  = (const float*)d_in[5];
  const float* wq    = (const float*)d_in[6];
  const float* wk    = (const float*)d_in[7];
  const float* wv    = (const float*)d_in[8];
  const float* bq    = (const float*)d_in[9];
  const float* bk    = (const float*)d_in[10];
  const float* bv    = (const float*)d_in[11];
  const float* projw = (const float*)d_in[12];
  const float* projb = (const float*)d_in[13];
  const float* ln2g  = (const float*)d_in[14];
  const float* ln2b  = (const float*)d_in[15];
  const float* ff1w  = (const float*)d_in[16];
  const float* ff1b  = (const float*)d_in[17];
  const float* ff2w  = (const float*)d_in[18];
  const float* ff2b  = (const float*)d_in[19];
  const float* lnfg  = (const float*)d_in[20];
  const float* lnfb  = (const float*)d_in[21];
  const float* headw = (const float*)d_in[22];
  const float* headb = (const float*)d_in[23];

  if (ws_size < 88080384ULL) return;  // need 84 MB scratch; fail loudly (output stays poison)

  char* w = (char*)d_ws;
  unsigned short* idxb   = (unsigned short*)w; w += (long)2048 * 2048 * 2;
  unsigned short* wembT  = (unsigned short*)w; w += (long)1024 * 2048 * 2;
  unsigned short* wheadT = (unsigned short*)w; w += (long)2048 * 1024 * 2;
  unsigned short* wqkvT  = (unsigned short*)w; w += (long)3072 * 1024 * 2;
  unsigned short* wprojT = (unsigned short*)w; w += (long)1024 * 1024 * 2;
  unsigned short* wff1T  = (unsigned short*)w; w += (long)4096 * 1024 * 2;
  unsigned short* wff2T  = (unsigned short*)w; w += (long)1024 * 4096 * 2;
  float*          xbuf   = (float*)w;          w += (long)2048 * 1024 * 4;
  unsigned short* hbuf   = (unsigned short*)w; w += (long)2048 * 1024 * 2;
  unsigned short* qkvb   = (unsigned short*)w; w += (long)2048 * 3072 * 2;
  unsigned short* ybuf   = (unsigned short*)w; w += (long)2048 * 1024 * 2;
  unsigned short* ffb    = (unsigned short*)w; w += (long)2048 * 4096 * 2;

  dim3 b256(256), b32x8(32, 8);

  // embedding: x = idx @ tok_w + tok_b + pos_emb
  f2b_kernel<<<2048, b256, 0, stream>>>(idx, idxb, 524288);
  tpack_kernel<<<dim3(32, 64, 1), b32x8, 0, stream>>>(tok_w, wembT, 1024, 2048, 0, 0);
  gemm_bt<2><<<dim3(8, 32), b256, 0, stream>>>(idxb, wembT, 2048, 1024, 2048, 0,
                                               tok_b, nullptr, nullptr, pos, xbuf, nullptr);

  for (int l = 0; l < 8; l++) {
    // pack this layer's weights (bf16, transposed to [N][K])
    tpack_kernel<<<dim3(2, 32, 16), b32x8, 0, stream>>>(wq + (long)l * 16 * 65536, wqkvT,
                                                        64, 1024, 65536, 65536);
    tpack_kernel<<<dim3(2, 32, 16), b32x8, 0, stream>>>(wk + (long)l * 16 * 65536, wqkvT + 1024 * 1024,
                                                        64, 1024, 65536, 65536);
    tpack_kernel<<<dim3(2, 32, 16), b32x8, 0, stream>>>(wv + (long)l * 16 * 65536, wqkvT + 2048 * 1024,
                                                        64, 1024, 65536, 65536);
    tpack_kernel<<<dim3(32, 32, 1), b32x8, 0, stream>>>(projw + (long)l * 1048576, wprojT, 1024, 1024, 0, 0);
    tpack_kernel<<<dim3(128, 32, 1), b32x8, 0, stream>>>(ff1w + (long)l * 4194304, wff1T, 4096, 1024, 0, 0);
    tpack_kernel<<<dim3(32, 128, 1), b32x8, 0, stream>>>(ff2w + (long)l * 4194304, wff2T, 1024, 4096, 0, 0);

    ln_kernel<<<2048, b256, 0, stream>>>(xbuf, ln1g + l * 1024, ln1b + l * 1024, hbuf);
    gemm_bt<4><<<dim3(24, 16), b256, 0, stream>>>(hbuf, wqkvT, 2048, 3072, 1024, 1,
                                                  bq + l * 1024, bk + l * 1024, bv + l * 1024,
                                                  nullptr, nullptr, qkvb);
    attn_kernel<<<8192, b256, 0, stream>>>(qkvb, ybuf);
    gemm_bt<2><<<dim3(8, 32), b256, 0, stream>>>(ybuf, wprojT, 2048, 1024, 1024, 3,
                                                 projb + l * 1024, nullptr, nullptr, nullptr, xbuf, nullptr);
    ln_kernel<<<2048, b256, 0, stream>>>(xbuf, ln2g + l * 1024, ln2b + l * 1024, hbuf);
    gemm_bt<4><<<dim3(32, 16), b256, 0, stream>>>(hbuf, wff1T, 2048, 4096, 1024, 2,
                                                  ff1b + l * 4096, nullptr, nullptr, nullptr, nullptr, ffb);
    gemm_bt<2><<<dim3(8, 32), b256, 0, stream>>>(ffb, wff2T, 2048, 1024, 4096, 3,
                                                 ff2b + l * 1024, nullptr, nullptr, nullptr, xbuf, nullptr);
  }

  tpack_kernel<<<dim3(64, 32, 1), b32x8, 0, stream>>>(headw, wheadT, 2048, 1024, 0, 0);
  ln_kernel<<<2048, b256, 0, stream>>>(xbuf, lnfg, lnfb, hbuf);
  gemm_bt<4><<<dim3(16, 16), b256, 0, stream>>>(hbuf, wheadT, 2048, 2048, 1024, 4,
                                                headb, nullptr, nullptr, nullptr, (float*)d_out, nullptr);
}

// Round 2
// 3163.893 us; speedup vs baseline: 2.3294x; 2.3294x over previous
//
#include <hip/hip_runtime.h>

// Transformer forward, MI355X gfx950.
// B=2 T=1024 V=2048 D=1024 H=16 DK=64 L=8. All inputs fp32; compute in bf16 MFMA
// with fp32 accumulation; residual stream kept fp32.

typedef __attribute__((ext_vector_type(8))) short v8s;   // 8 bf16 in 4 VGPRs (MFMA A/B frag)
typedef __attribute__((ext_vector_type(4))) float v4f;   // MFMA C/D frag

#define DEV static __device__ __forceinline__
#define L2E 1.4426950408889634f

DEV float b2f(unsigned short u) { return __uint_as_float(((unsigned)u) << 16); }
DEV unsigned short f2bf(float f) {            // round-to-nearest-even fp32->bf16
  unsigned u = __float_as_uint(f);
  u += 0x7fff + ((u >> 16) & 1);
  return (unsigned short)(u >> 16);
}

// ---------------------------------------------------------------- fp32 -> bf16 bulk convert
__global__ __launch_bounds__(256) void f2b_kernel(const float* __restrict__ in,
                                                  unsigned short* __restrict__ out, int n8) {
  int i = blockIdx.x * 256 + threadIdx.x;
  if (i >= n8) return;
  const float4* ip = (const float4*)in;
  float4 a = ip[2 * i], b = ip[2 * i + 1];
  uint4 u;
  u.x = (unsigned)f2bf(a.x) | ((unsigned)f2bf(a.y) << 16);
  u.y = (unsigned)f2bf(a.z) | ((unsigned)f2bf(a.w) << 16);
  u.z = (unsigned)f2bf(b.x) | ((unsigned)f2bf(b.y) << 16);
  u.w = (unsigned)f2bf(b.z) | ((unsigned)f2bf(b.w) << 16);
  ((uint4*)out)[i] = u;
}

// ---------------------------------------------------------------- transpose+convert pack
__global__ __launch_bounds__(256) void tpack_kernel(const float* __restrict__ in,
                                                    unsigned short* __restrict__ out,
                                                    int in_rs, int out_rs, long in_zs, long out_zs) {
  __shared__ float tl[32][33];
  const float* ip = in + (long)blockIdx.z * in_zs;
  unsigned short* op = out + (long)blockIdx.z * out_zs;
  int c0 = blockIdx.x * 32, r0 = blockIdx.y * 32;
  int tx = threadIdx.x, ty = threadIdx.y;
#pragma unroll
  for (int i = 0; i < 4; i++) {
    int r = ty + i * 8;
    tl[r][tx] = ip[(long)(r0 + r) * in_rs + c0 + tx];
  }
  __syncthreads();
#pragma unroll
  for (int i = 0; i < 4; i++) {
    int cr = ty + i * 8;
    op[(long)(c0 + cr) * out_rs + r0 + tx] = f2bf(tl[tx][cr]);
  }
}

// ---------------------------------------------------------------- LayerNorm (fp32 in, bf16 out)
__global__ __launch_bounds__(256) void ln_kernel(const float* __restrict__ x,
                                                 const float* __restrict__ g,
                                                 const float* __restrict__ b,
                                                 unsigned short* __restrict__ out) {
  int row = blockIdx.x, t = threadIdx.x;
  const float4* xr = (const float4*)(x + (long)row * 1024);
  float4 v = xr[t];
  float s = v.x + v.y + v.z + v.w;
  float ss = v.x * v.x + v.y * v.y + v.z * v.z + v.w * v.w;
#pragma unroll
  for (int o = 32; o > 0; o >>= 1) { s += __shfl_xor(s, o); ss += __shfl_xor(ss, o); }
  __shared__ float ps[4], pss[4];
  int wid = t >> 6;
  if ((t & 63) == 0) { ps[wid] = s; pss[wid] = ss; }
  __syncthreads();
  s = ps[0] + ps[1] + ps[2] + ps[3];
  ss = pss[0] + pss[1] + pss[2] + pss[3];
  float mean = s * (1.0f / 1024.0f);
  float var = ss * (1.0f / 1024.0f) - mean * mean;
  float rstd = rsqrtf(var + 1e-5f);
  float4 gg = ((const float4*)g)[t];
  float4 bb = ((const float4*)b)[t];
  unsigned o0 = f2bf((v.x - mean) * rstd * gg.x + bb.x);
  unsigned o1 = f2bf((v.y - mean) * rstd * gg.y + bb.y);
  unsigned o2 = f2bf((v.z - mean) * rstd * gg.z + bb.z);
  unsigned o3 = f2bf((v.w - mean) * rstd * gg.w + bb.w);
  uint2 u; u.x = o0 | (o1 << 16); u.y = o2 | (o3 << 16);
  ((uint2*)(out + (long)row * 1024))[t] = u;
}

// ---------------------------------------------------------------- bf16 MFMA GEMM, B transposed
// C[M,N] = A[M,K] * Bt[N,K]^T (+epilogue). BM = MT*32, BN=128, BK=64.
// modes: 0=embed(+tok_b+pos_emb -> f32 x) 1=qkv(+b -> bf16) 2=ff1(+b,relu -> bf16)
//        3=resid(x += acc+b, f32)         4=head(+b -> f32 out)
template <int MT>
__global__ __launch_bounds__(256) void gemm_bt(const unsigned short* __restrict__ A,
                                               const unsigned short* __restrict__ Bt,
                                               int M, int N, int K, int mode,
                                               const float* __restrict__ bias0,
                                               const float* __restrict__ bias1,
                                               const float* __restrict__ bias2,
                                               const float* __restrict__ posemb,
                                               float* __restrict__ fout,
                                               unsigned short* __restrict__ bout) {
  __shared__ unsigned short As[MT * 32 * 72];
  __shared__ unsigned short Bs[128 * 72];
  int tid = threadIdx.x;
  int lane = tid & 63, wid = tid >> 6;
  int wm = (wid >> 1) * MT * 16, wn = (wid & 1) * 64;
  int ln15 = lane & 15, q8 = (lane >> 4) * 8;
  int row0 = blockIdx.y * (MT * 32), n0 = blockIdx.x * 128;

  int rs = tid >> 3, cs = (tid & 7) * 8;
  const unsigned short* Ap[MT]; const unsigned short* Bp[4];
  unsigned short* Al[MT]; unsigned short* Bl[4];
#pragma unroll
  for (int j = 0; j < MT; j++) {
    int r = j * 32 + rs;
    Ap[j] = A + (long)(row0 + r) * K + cs;
    Al[j] = &As[r * 72 + cs];
  }
#pragma unroll
  for (int j = 0; j < 4; j++) {
    int r = j * 32 + rs;
    Bp[j] = Bt + (long)(n0 + r) * K + cs;
    Bl[j] = &Bs[r * 72 + cs];
  }

  v4f acc[MT][4];
  v4f zero = {0.f, 0.f, 0.f, 0.f};
#pragma unroll
  for (int m = 0; m < MT; m++)
#pragma unroll
    for (int n = 0; n < 4; n++) acc[m][n] = zero;

  for (int k0 = 0; k0 < K; k0 += 64) {
    if (k0) __syncthreads();
#pragma unroll
    for (int j = 0; j < MT; j++) { uint4 ua = *(const uint4*)(Ap[j] + k0); *(uint4*)Al[j] = ua; }
#pragma unroll
    for (int j = 0; j < 4; j++) { uint4 ub = *(const uint4*)(Bp[j] + k0); *(uint4*)Bl[j] = ub; }
    __syncthreads();
#pragma unroll
    for (int ks = 0; ks < 2; ks++) {
      int ko = ks * 32 + q8;
      v8s af[MT], bfv[4];
#pragma unroll
      for (int m = 0; m < MT; m++) af[m] = *(const v8s*)&As[(wm + m * 16 + ln15) * 72 + ko];
#pragma unroll
      for (int n = 0; n < 4; n++) bfv[n] = *(const v8s*)&Bs[(wn + n * 16 + ln15) * 72 + ko];
#pragma unroll
      for (int m = 0; m < MT; m++)
#pragma unroll
        for (int n = 0; n < 4; n++)
          acc[m][n] = __builtin_amdgcn_mfma_f32_16x16x32_bf16(af[m], bfv[n], acc[m][n], 0, 0, 0);
    }
  }

  int q4 = (lane >> 4) * 4;
#pragma unroll
  for (int m = 0; m < MT; m++) {
#pragma unroll
    for (int n = 0; n < 4; n++) {
      int gn = n0 + wn + n * 16 + ln15;
      float bcol;
      if (mode == 1)
        bcol = gn < 1024 ? bias0[gn] : (gn < 2048 ? bias1[gn - 1024] : bias2[gn - 2048]);
      else
        bcol = bias0[gn];
#pragma unroll
      for (int r = 0; r < 4; r++) {
        int gm = row0 + wm + m * 16 + q4 + r;
        float v = acc[m][n][r] + bcol;
        if (mode == 0) {
          fout[(long)gm * N + gn] = v + posemb[(long)(gm & 1023) * 1024 + gn];
        } else if (mode == 1) {
          bout[(long)gm * N + gn] = f2bf(v);
        } else if (mode == 2) {
          bout[(long)gm * N + gn] = f2bf(fmaxf(v, 0.f));
        } else if (mode == 3) {
          fout[(long)gm * N + gn] += v;
        } else {
          fout[(long)gm * N + gn] = v;
        }
      }
    }
  }
}

// ---------------------------------------------------------------- causal flash attention (MFMA)
// qkv: [B*T, 3072] bf16, cols [0,1024)=Q [1024,2048)=K [2048,3072)=V, each h-major (h*64+dk).
// grid (16 q-tiles, 32 bh), 256 threads. Block handles 64 Q rows; wave w rows [w*16, w*16+16).
// KV tiles of 64 keys staged in LDS: K as [key][dk] stride 72; V transposed [dk][s] stride 72
// with XOR swizzle (s ^ ((dk>>3)*8)) keeping ds_read_b128 alignment. P (C-layout) round-trips
// through per-wave LDS scratch to become the PV A-operand (m120 pattern).
__global__ __launch_bounds__(256) void attn_kernel(const unsigned short* __restrict__ qkv,
                                                   unsigned short* __restrict__ Y) {
  __shared__ unsigned short Ks[64 * 72];
  __shared__ unsigned short Vts[64 * 72];
  __shared__ unsigned short Ps[4][16 * 72];

  int tid = threadIdx.x, wid = tid >> 6, lane = tid & 63;
  int ln15 = lane & 15, quad = lane >> 4, q8 = quad * 8, q4 = quad * 4;
  int qt = 15 - blockIdx.x;                 // heavy blocks dispatched first
  int bh = blockIdx.y, b = bh >> 4, h = bh & 15;
  long base = (long)b * 1024 * 3072 + h * 64;

  // Q fragments (16 rows x 64 k), pre-scaled by DK^-0.5 = 0.125 (exact in bf16)
  int qrow0 = qt * 64 + wid * 16;
  v8s qf[2];
#pragma unroll
  for (int ks = 0; ks < 2; ks++) {
    v8s v = *(const v8s*)(qkv + base + (long)(qrow0 + ln15) * 3072 + ks * 32 + q8);
#pragma unroll
    for (int j = 0; j < 8; j++) {
      float f = b2f((unsigned short)v[j]) * 0.125f;
      v[j] = (short)f2bf(f);
    }
    qf[ks] = v;
  }

  v4f Oacc[4];
  v4f zero = {0.f, 0.f, 0.f, 0.f};
#pragma unroll
  for (int n = 0; n < 4; n++) Oacc[n] = zero;
  float m_r[4] = {-INFINITY, -INFINITY, -INFINITY, -INFINITY};
  float l_r[4] = {0.f, 0.f, 0.f, 0.f};

  int krow = tid >> 3, kcol = (tid & 7) * 8;

  for (int kv = 0; kv <= qt; kv++) {
    int s0 = kv * 64;
    __syncthreads();                        // previous tile fully consumed
#pragma unroll
    for (int p = 0; p < 2; p++) {
      int row = krow + p * 32;
      const unsigned short* gk = qkv + base + (long)(s0 + row) * 3072 + 1024 + kcol;
      *(uint4*)&Ks[row * 72 + kcol] = *(const uint4*)gk;
      uint4 vv = *(const uint4*)(qkv + base + (long)(s0 + row) * 3072 + 2048 + kcol);
      unsigned short e[8];
      e[0] = (unsigned short)vv.x; e[1] = (unsigned short)(vv.x >> 16);
      e[2] = (unsigned short)vv.y; e[3] = (unsigned short)(vv.y >> 16);
      e[4] = (unsigned short)vv.z; e[5] = (unsigned short)(vv.z >> 16);
      e[6] = (unsigned short)vv.w; e[7] = (unsigned short)(vv.w >> 16);
      int sw = row ^ kcol;                  // kcol == ((dk>>3)*8) for dk in [kcol,kcol+8)
#pragma unroll
      for (int j = 0; j < 8; j++) Vts[(kcol + j) * 72 + sw] = e[j];
    }
    __syncthreads();

    // S = (Q*scale) K^T : wave computes 16x64
    v4f S[4];
#pragma unroll
    for (int n = 0; n < 4; n++) S[n] = zero;
#pragma unroll
    for (int ks = 0; ks < 2; ks++) {
#pragma unroll
      for (int n = 0; n < 4; n++) {
        v8s kf = *(const v8s*)&Ks[(n * 16 + ln15) * 72 + ks * 32 + q8];
        S[n] = __builtin_amdgcn_mfma_f32_16x16x32_bf16(qf[ks], kf, S[n], 0, 0, 0);
      }
    }
    if (kv == qt) {                         // causal mask on diagonal tile
#pragma unroll
      for (int n = 0; n < 4; n++) {
        int sc = n * 16 + ln15;
#pragma unroll
        for (int r = 0; r < 4; r++)
          if (sc > wid * 16 + q4 + r) S[n][r] = -INFINITY;
      }
    }

    // online softmax (rows live across 16-lane groups; C layout row=q4+r, col=ln15)
    float p[4][4];
#pragma unroll
    for (int r = 0; r < 4; r++) {
      float rowm = fmaxf(fmaxf(S[0][r], S[1][r]), fmaxf(S[2][r], S[3][r]));
#pragma unroll
      for (int o = 8; o > 0; o >>= 1) rowm = fmaxf(rowm, __shfl_xor(rowm, o));
      float mnew = fmaxf(m_r[r], rowm);
      float alpha = exp2f((m_r[r] - mnew) * L2E);
      m_r[r] = mnew;
      float rsum = 0.f;
#pragma unroll
      for (int n = 0; n < 4; n++) {
        float pe = exp2f((S[n][r] - mnew) * L2E);
        p[n][r] = pe;
        rsum += pe;
      }
#pragma unroll
      for (int o = 8; o > 0; o >>= 1) rsum += __shfl_xor(rsum, o);
      l_r[r] = l_r[r] * alpha + rsum;
#pragma unroll
      for (int n = 0; n < 4; n++) Oacc[n][r] *= alpha;
    }

    // P: C-layout -> LDS -> A-frag layout
#pragma unroll
    for (int n = 0; n < 4; n++)
#pragma unroll
      for (int r = 0; r < 4; r++)
        Ps[wid][(q4 + r) * 72 + n * 16 + ln15] = f2bf(p[n][r]);

#pragma unroll
    for (int ks = 0; ks < 2; ks++) {
      v8s pf = *(const v8s*)&Ps[wid][ln15 * 72 + ks * 32 + q8];
#pragma unroll
      for (int n = 0; n < 4; n++) {
        int dk = n * 16 + ln15;
        int soff = (ks * 32 + q8) ^ ((dk >> 3) * 8);
        v8s vf = *(const v8s*)&Vts[dk * 72 + soff];
        Oacc[n] = __builtin_amdgcn_mfma_f32_16x16x32_bf16(pf, vf, Oacc[n], 0, 0, 0);
      }
    }
  }

  // epilogue: O/l -> Y
#pragma unroll
  for (int r = 0; r < 4; r++) {
    float inv = 1.0f / l_r[r];
    int t = qrow0 + q4 + r;
#pragma unroll
    for (int n = 0; n < 4; n++)
      Y[((long)(b * 1024 + t)) * 1024 + h * 64 + n * 16 + ln15] = f2bf(Oacc[n][r] * inv);
  }
}

// ---------------------------------------------------------------- host
extern "C" void kernel_launch(void* const* d_in, const int* in_sizes, int n_in,
                              void* d_out, int out_size, void* d_ws, size_t ws_size,
                              hipStream_t stream) {
  const float* idx   = (const float*)d_in[0];
  const float* tok_w = (const float*)d_in[1];
  const float* tok_b = (const float*)d_in[2];
  const float* pos   = (const float*)d_in[3];
  const float* ln1g  = (const float*)d_in[4];
  const float* ln1b  = (const float*)d_in[5];
  const float* wq    = (const float*)d_in[6];
  const float* wk    = (const float*)d_in[7];
  const float* wv    = (const float*)d_in[8];
  const float* bq    = (const float*)d_in[9];
  const float* bk    = (const float*)d_in[10];
  const float* bv    = (const float*)d_in[11];
  const float* projw = (const float*)d_in[12];
  const float* projb = (const float*)d_in[13];
  const float* ln2g  = (const float*)d_in[14];
  const float* ln2b  = (const float*)d_in[15];
  const float* ff1w  = (const float*)d_in[16];
  const float* ff1b  = (const float*)d_in[17];
  const float* ff2w  = (const float*)d_in[18];
  const float* ff2b  = (const float*)d_in[19];
  const float* lnfg  = (const float*)d_in[20];
  const float* lnfb  = (const float*)d_in[21];
  const float* headw = (const float*)d_in[22];
  const float* headb = (const float*)d_in[23];

  if (ws_size < 88080384ULL) return;

  char* w = (char*)d_ws;
  unsigned short* idxb   = (unsigned short*)w; w += (long)2048 * 2048 * 2;
  unsigned short* wembT  = (unsigned short*)w; w += (long)1024 * 2048 * 2;
  unsigned short* wheadT = (unsigned short*)w; w += (long)2048 * 1024 * 2;
  unsigned short* wqkvT  = (unsigned short*)w; w += (long)3072 * 1024 * 2;
  unsigned short* wprojT = (unsigned short*)w; w += (long)1024 * 1024 * 2;
  unsigned short* wff1T  = (unsigned short*)w; w += (long)4096 * 1024 * 2;
  unsigned short* wff2T  = (unsigned short*)w; w += (long)1024 * 4096 * 2;
  float*          xbuf   = (float*)w;          w += (long)2048 * 1024 * 4;
  unsigned short* hbuf   = (unsigned short*)w; w += (long)2048 * 1024 * 2;
  unsigned short* qkvb   = (unsigned short*)w; w += (long)2048 * 3072 * 2;
  unsigned short* ybuf   = (unsigned short*)w; w += (long)2048 * 1024 * 2;
  unsigned short* ffb    = (unsigned short*)w; w += (long)2048 * 4096 * 2;

  dim3 b256(256), b32x8(32, 8);

  f2b_kernel<<<2048, b256, 0, stream>>>(idx, idxb, 524288);
  tpack_kernel<<<dim3(32, 64, 1), b32x8, 0, stream>>>(tok_w, wembT, 1024, 2048, 0, 0);
  gemm_bt<2><<<dim3(8, 32), b256, 0, stream>>>(idxb, wembT, 2048, 1024, 2048, 0,
                                               tok_b, nullptr, nullptr, pos, xbuf, nullptr);

  for (int l = 0; l < 8; l++) {
    tpack_kernel<<<dim3(2, 32, 16), b32x8, 0, stream>>>(wq + (long)l * 16 * 65536, wqkvT,
                                                        64, 1024, 65536, 65536);
    tpack_kernel<<<dim3(2, 32, 16), b32x8, 0, stream>>>(wk + (long)l * 16 * 65536, wqkvT + 1024 * 1024,
                                                        64, 1024, 65536, 65536);
    tpack_kernel<<<dim3(2, 32, 16), b32x8, 0, stream>>>(wv + (long)l * 16 * 65536, wqkvT + 2048 * 1024,
                                                        64, 1024, 65536, 65536);
    tpack_kernel<<<dim3(32, 32, 1), b32x8, 0, stream>>>(projw + (long)l * 1048576, wprojT, 1024, 1024, 0, 0);
    tpack_kernel<<<dim3(128, 32, 1), b32x8, 0, stream>>>(ff1w + (long)l * 4194304, wff1T, 4096, 1024, 0, 0);
    tpack_kernel<<<dim3(32, 128, 1), b32x8, 0, stream>>>(ff2w + (long)l * 4194304, wff2T, 1024, 4096, 0, 0);

    ln_kernel<<<2048, b256, 0, stream>>>(xbuf, ln1g + l * 1024, ln1b + l * 1024, hbuf);
    gemm_bt<4><<<dim3(24, 16), b256, 0, stream>>>(hbuf, wqkvT, 2048, 3072, 1024, 1,
                                                  bq + l * 1024, bk + l * 1024, bv + l * 1024,
                                                  nullptr, nullptr, qkvb);
    attn_kernel<<<dim3(16, 32), b256, 0, stream>>>(qkvb, ybuf);
    gemm_bt<2><<<dim3(8, 32), b256, 0, stream>>>(ybuf, wprojT, 2048, 1024, 1024, 3,
                                                 projb + l * 1024, nullptr, nullptr, nullptr, xbuf, nullptr);
    ln_kernel<<<2048, b256, 0, stream>>>(xbuf, ln2g + l * 1024, ln2b + l * 1024, hbuf);
    gemm_bt<4><<<dim3(32, 16), b256, 0, stream>>>(hbuf, wff1T, 2048, 4096, 1024, 2,
                                                  ff1b + l * 4096, nullptr, nullptr, nullptr, nullptr, ffb);
    gemm_bt<2><<<dim3(8, 32), b256, 0, stream>>>(ffb, wff2T, 2048, 1024, 4096, 3,
                                                 ff2b + l * 1024, nullptr, nullptr, nullptr, xbuf, nullptr);
  }

  tpack_kernel<<<dim3(64, 32, 1), b32x8, 0, stream>>>(headw, wheadT, 2048, 1024, 0, 0);
  ln_kernel<<<2048, b256, 0, stream>>>(xbuf, lnfg, lnfb, hbuf);
  gemm_bt<4><<<dim3(16, 16), b256, 0, stream>>>(hbuf, wheadT, 2048, 2048, 1024, 4,
                                                headb, nullptr, nullptr, nullptr, (float*)d_out, nullptr);
}

// Round 3
// 2080.014 us; speedup vs baseline: 3.5432x; 1.5211x over previous
//
#include <hip/hip_runtime.h>

// Transformer forward, MI355X gfx950.
// B=2 T=1024 V=2048 D=1024 H=16 DK=64 L=8. All inputs fp32; compute in bf16 MFMA
// with fp32 accumulation; residual stream kept fp32.

typedef __attribute__((ext_vector_type(8))) short v8s;   // 8 bf16 in 4 VGPRs (MFMA A/B frag)
typedef __attribute__((ext_vector_type(4))) float v4f;   // MFMA C/D frag

#define DEV static __device__ __forceinline__
#define L2E 1.4426950408889634f

DEV float b2f(unsigned short u) { return __uint_as_float(((unsigned)u) << 16); }
DEV unsigned short f2bf(float f) {            // round-to-nearest-even fp32->bf16
  unsigned u = __float_as_uint(f);
  u += 0x7fff + ((u >> 16) & 1);
  return (unsigned short)(u >> 16);
}

// async global->LDS, 16B per lane; LDS dest = wave-uniform base + lane*16 (m97/m104)
DEV void gload_lds16(const unsigned short* g, unsigned short* l) {
  __builtin_amdgcn_global_load_lds((const __attribute__((address_space(1))) void*)g,
                                   (__attribute__((address_space(3))) void*)l, 16, 0, 0);
}

// ---------------------------------------------------------------- fp32 -> bf16 bulk convert
__global__ __launch_bounds__(256) void f2b_kernel(const float* __restrict__ in,
                                                  unsigned short* __restrict__ out, int n8) {
  int i = blockIdx.x * 256 + threadIdx.x;
  if (i >= n8) return;
  const float4* ip = (const float4*)in;
  float4 a = ip[2 * i], b = ip[2 * i + 1];
  uint4 u;
  u.x = (unsigned)f2bf(a.x) | ((unsigned)f2bf(a.y) << 16);
  u.y = (unsigned)f2bf(a.z) | ((unsigned)f2bf(a.w) << 16);
  u.z = (unsigned)f2bf(b.x) | ((unsigned)f2bf(b.y) << 16);
  u.w = (unsigned)f2bf(b.z) | ((unsigned)f2bf(b.w) << 16);
  ((uint4*)out)[i] = u;
}

// ---------------------------------------------------------------- transpose+convert pack
__global__ __launch_bounds__(256) void tpack_kernel(const float* __restrict__ in,
                                                    unsigned short* __restrict__ out,
                                                    int in_rs, int out_rs, long in_zs, long out_zs) {
  __shared__ float tl[32][33];
  const float* ip = in + (long)blockIdx.z * in_zs;
  unsigned short* op = out + (long)blockIdx.z * out_zs;
  int c0 = blockIdx.x * 32, r0 = blockIdx.y * 32;
  int tx = threadIdx.x, ty = threadIdx.y;
#pragma unroll
  for (int i = 0; i < 4; i++) {
    int r = ty + i * 8;
    tl[r][tx] = ip[(long)(r0 + r) * in_rs + c0 + tx];
  }
  __syncthreads();
#pragma unroll
  for (int i = 0; i < 4; i++) {
    int cr = ty + i * 8;
    op[(long)(c0 + cr) * out_rs + r0 + tx] = f2bf(tl[tx][cr]);
  }
}

// ---------------------------------------------------------------- LayerNorm (fp32 in, bf16 out)
__global__ __launch_bounds__(256) void ln_kernel(const float* __restrict__ x,
                                                 const float* __restrict__ g,
                                                 const float* __restrict__ b,
                                                 unsigned short* __restrict__ out) {
  int row = blockIdx.x, t = threadIdx.x;
  const float4* xr = (const float4*)(x + (long)row * 1024);
  float4 v = xr[t];
  float s = v.x + v.y + v.z + v.w;
  float ss = v.x * v.x + v.y * v.y + v.z * v.z + v.w * v.w;
#pragma unroll
  for (int o = 32; o > 0; o >>= 1) { s += __shfl_xor(s, o); ss += __shfl_xor(ss, o); }
  __shared__ float ps[4], pss[4];
  int wid = t >> 6;
  if ((t & 63) == 0) { ps[wid] = s; pss[wid] = ss; }
  __syncthreads();
  s = ps[0] + ps[1] + ps[2] + ps[3];
  ss = pss[0] + pss[1] + pss[2] + pss[3];
  float mean = s * (1.0f / 1024.0f);
  float var = ss * (1.0f / 1024.0f) - mean * mean;
  float rstd = rsqrtf(var + 1e-5f);
  float4 gg = ((const float4*)g)[t];
  float4 bb = ((const float4*)b)[t];
  unsigned o0 = f2bf((v.x - mean) * rstd * gg.x + bb.x);
  unsigned o1 = f2bf((v.y - mean) * rstd * gg.y + bb.y);
  unsigned o2 = f2bf((v.z - mean) * rstd * gg.z + bb.z);
  unsigned o3 = f2bf((v.w - mean) * rstd * gg.w + bb.w);
  uint2 u; u.x = o0 | (o1 << 16); u.y = o2 | (o3 << 16);
  ((uint2*)(out + (long)row * 1024))[t] = u;
}

// ---------------------------------------------------------------- bf16 MFMA GEMM v2
// C[M,N] = A[M,K] * Bt[N,K]^T (+epilogue). BM=128 BN=64 BK=64; 4 waves 2x2, each 64x32.
// grid (N/64, M/128, splits); split z covers K range [z*kPer, (z+1)*kPer).
// Staging via global_load_lds width=16 into unpadded [row][64] LDS tiles with XOR
// col-chunk swizzle (phys_chunk = log_chunk ^ (row&7)) applied at the global address:
// staging writes are contiguous (conflict-free by construction), ds_read_b128 frag reads
// spread uniformly over all 32 banks.
// modes: 0=embed(atomic += A*B [+tok_b+pos at z==0])   1=qkv(+b -> bf16)
//        2=ff1(+b,relu -> bf16)  3=resid(atomic += [+b at z==0], f32)  4=head(+b -> f32)
__global__ __launch_bounds__(256) void gemm2(const unsigned short* __restrict__ A,
                                             const unsigned short* __restrict__ Bt,
                                             int N, int K, int kPer, int mode,
                                             const float* __restrict__ bias0,
                                             const float* __restrict__ bias1,
                                             const float* __restrict__ bias2,
                                             const float* __restrict__ posemb,
                                             float* __restrict__ fout,
                                             unsigned short* __restrict__ bout) {
  __shared__ unsigned short As[128 * 64];
  __shared__ unsigned short Bs[64 * 64];
  int tid = threadIdx.x;
  int lane = tid & 63, wid = tid >> 6;
  int ln15 = lane & 15, quad = lane >> 4;
  int wm = (wid & 1) * 64, wn = (wid >> 1) * 32;
  int row0 = blockIdx.y * 128, n0 = blockIdx.x * 64;
  int k0beg = blockIdx.z * kPer, k0end = k0beg + kPer;

  // staging lane mapping: lane -> (row lr, phys chunk lc); data = logical chunk lc^lr
  int lr = lane >> 3, lc = lane & 7;
  int gcol = ((lc ^ lr) * 8);

  const unsigned short* Ag[4]; unsigned short* Al[4];
#pragma unroll
  for (int p = 0; p < 4; p++) {
    int r = wid * 32 + p * 8;
    Ag[p] = A + (long)(row0 + r + lr) * K + gcol;
    Al[p] = &As[r * 64];
  }
  const unsigned short* Bg[2]; unsigned short* Bl[2];
#pragma unroll
  for (int p = 0; p < 2; p++) {
    int r = wid * 16 + p * 8;
    Bg[p] = Bt + (long)(n0 + r + lr) * K + gcol;
    Bl[p] = &Bs[r * 64];
  }

  v4f acc[4][2];
  v4f zero = {0.f, 0.f, 0.f, 0.f};
#pragma unroll
  for (int m = 0; m < 4; m++)
#pragma unroll
    for (int n = 0; n < 2; n++) acc[m][n] = zero;

  int l7 = ln15 & 7;
  for (int k0 = k0beg; k0 < k0end; k0 += 64) {
    if (k0 != k0beg) __syncthreads();
#pragma unroll
    for (int p = 0; p < 4; p++) gload_lds16(Ag[p] + k0, Al[p]);
#pragma unroll
    for (int p = 0; p < 2; p++) gload_lds16(Bg[p] + k0, Bl[p]);
    __syncthreads();
#pragma unroll
    for (int ks = 0; ks < 2; ks++) {
      int pc = 8 * (((ks << 2) | quad) ^ l7);   // swizzled phys col (shorts)
      v8s af[4], bfv[2];
#pragma unroll
      for (int m = 0; m < 4; m++) af[m] = *(const v8s*)&As[(wm + m * 16 + ln15) * 64 + pc];
#pragma unroll
      for (int n = 0; n < 2; n++) bfv[n] = *(const v8s*)&Bs[(wn + n * 16 + ln15) * 64 + pc];
#pragma unroll
      for (int m = 0; m < 4; m++)
#pragma unroll
        for (int n = 0; n < 2; n++)
          acc[m][n] = __builtin_amdgcn_mfma_f32_16x16x32_bf16(af[m], bfv[n], acc[m][n], 0, 0, 0);
    }
  }

  // epilogue: C/D layout col = lane&15, row = quad*4 + reg
  bool z0 = (blockIdx.z == 0);
  int q4 = quad * 4;
#pragma unroll
  for (int m = 0; m < 4; m++) {
#pragma unroll
    for (int n = 0; n < 2; n++) {
      int gn = n0 + wn + n * 16 + ln15;
      float bcol;
      if (mode == 1)
        bcol = gn < 1024 ? bias0[gn] : (gn < 2048 ? bias1[gn - 1024] : bias2[gn - 2048]);
      else
        bcol = bias0[gn];
#pragma unroll
      for (int r = 0; r < 4; r++) {
        int gm = row0 + wm + m * 16 + q4 + r;
        float v = acc[m][n][r];
        if (mode == 0) {
          if (z0) v += bcol + posemb[(long)(gm & 1023) * 1024 + gn];
          atomicAdd(&fout[(long)gm * N + gn], v);
        } else if (mode == 1) {
          bout[(long)gm * N + gn] = f2bf(v + bcol);
        } else if (mode == 2) {
          bout[(long)gm * N + gn] = f2bf(fmaxf(v + bcol, 0.f));
        } else if (mode == 3) {
          if (z0) v += bcol;
          atomicAdd(&fout[(long)gm * N + gn], v);
        } else {
          fout[(long)gm * N + gn] = v + bcol;
        }
      }
    }
  }
}

// ---------------------------------------------------------------- causal flash attention (MFMA)
__global__ __launch_bounds__(256) void attn_kernel(const unsigned short* __restrict__ qkv,
                                                   unsigned short* __restrict__ Y) {
  __shared__ unsigned short Ks[64 * 72];
  __shared__ unsigned short Vts[64 * 72];
  __shared__ unsigned short Ps[4][16 * 72];

  int tid = threadIdx.x, wid = tid >> 6, lane = tid & 63;
  int ln15 = lane & 15, quad = lane >> 4, q8 = quad * 8, q4 = quad * 4;
  int qt = 15 - blockIdx.x;                 // heavy blocks dispatched first
  int bh = blockIdx.y, b = bh >> 4, h = bh & 15;
  long base = (long)b * 1024 * 3072 + h * 64;

  int qrow0 = qt * 64 + wid * 16;
  v8s qf[2];
#pragma unroll
  for (int ks = 0; ks < 2; ks++) {
    v8s v = *(const v8s*)(qkv + base + (long)(qrow0 + ln15) * 3072 + ks * 32 + q8);
#pragma unroll
    for (int j = 0; j < 8; j++) {
      float f = b2f((unsigned short)v[j]) * 0.125f;
      v[j] = (short)f2bf(f);
    }
    qf[ks] = v;
  }

  v4f Oacc[4];
  v4f zero = {0.f, 0.f, 0.f, 0.f};
#pragma unroll
  for (int n = 0; n < 4; n++) Oacc[n] = zero;
  float m_r[4] = {-INFINITY, -INFINITY, -INFINITY, -INFINITY};
  float l_r[4] = {0.f, 0.f, 0.f, 0.f};

  int krow = tid >> 3, kcol = (tid & 7) * 8;

  for (int kv = 0; kv <= qt; kv++) {
    int s0 = kv * 64;
    __syncthreads();
#pragma unroll
    for (int p = 0; p < 2; p++) {
      int row = krow + p * 32;
      const unsigned short* gk = qkv + base + (long)(s0 + row) * 3072 + 1024 + kcol;
      *(uint4*)&Ks[row * 72 + kcol] = *(const uint4*)gk;
      uint4 vv = *(const uint4*)(qkv + base + (long)(s0 + row) * 3072 + 2048 + kcol);
      unsigned short e[8];
      e[0] = (unsigned short)vv.x; e[1] = (unsigned short)(vv.x >> 16);
      e[2] = (unsigned short)vv.y; e[3] = (unsigned short)(vv.y >> 16);
      e[4] = (unsigned short)vv.z; e[5] = (unsigned short)(vv.z >> 16);
      e[6] = (unsigned short)vv.w; e[7] = (unsigned short)(vv.w >> 16);
      int sw = row ^ kcol;
#pragma unroll
      for (int j = 0; j < 8; j++) Vts[(kcol + j) * 72 + sw] = e[j];
    }
    __syncthreads();

    v4f S[4];
#pragma unroll
    for (int n = 0; n < 4; n++) S[n] = zero;
#pragma unroll
    for (int ks = 0; ks < 2; ks++) {
#pragma unroll
      for (int n = 0; n < 4; n++) {
        v8s kf = *(const v8s*)&Ks[(n * 16 + ln15) * 72 + ks * 32 + q8];
        S[n] = __builtin_amdgcn_mfma_f32_16x16x32_bf16(qf[ks], kf, S[n], 0, 0, 0);
      }
    }
    if (kv == qt) {
#pragma unroll
      for (int n = 0; n < 4; n++) {
        int sc = n * 16 + ln15;
#pragma unroll
        for (int r = 0; r < 4; r++)
          if (sc > wid * 16 + q4 + r) S[n][r] = -INFINITY;
      }
    }

    float p[4][4];
#pragma unroll
    for (int r = 0; r < 4; r++) {
      float rowm = fmaxf(fmaxf(S[0][r], S[1][r]), fmaxf(S[2][r], S[3][r]));
#pragma unroll
      for (int o = 8; o > 0; o >>= 1) rowm = fmaxf(rowm, __shfl_xor(rowm, o));
      float mnew = fmaxf(m_r[r], rowm);
      float alpha = exp2f((m_r[r] - mnew) * L2E);
      m_r[r] = mnew;
      float rsum = 0.f;
#pragma unroll
      for (int n = 0; n < 4; n++) {
        float pe = exp2f((S[n][r] - mnew) * L2E);
        p[n][r] = pe;
        rsum += pe;
      }
#pragma unroll
      for (int o = 8; o > 0; o >>= 1) rsum += __shfl_xor(rsum, o);
      l_r[r] = l_r[r] * alpha + rsum;
#pragma unroll
      for (int n = 0; n < 4; n++) Oacc[n][r] *= alpha;
    }

#pragma unroll
    for (int n = 0; n < 4; n++)
#pragma unroll
      for (int r = 0; r < 4; r++)
        Ps[wid][(q4 + r) * 72 + n * 16 + ln15] = f2bf(p[n][r]);

#pragma unroll
    for (int ks = 0; ks < 2; ks++) {
      v8s pf = *(const v8s*)&Ps[wid][ln15 * 72 + ks * 32 + q8];
#pragma unroll
      for (int n = 0; n < 4; n++) {
        int dk = n * 16 + ln15;
        int soff = (ks * 32 + q8) ^ ((dk >> 3) * 8);
        v8s vf = *(const v8s*)&Vts[dk * 72 + soff];
        Oacc[n] = __builtin_amdgcn_mfma_f32_16x16x32_bf16(pf, vf, Oacc[n], 0, 0, 0);
      }
    }
  }

#pragma unroll
  for (int r = 0; r < 4; r++) {
    float inv = 1.0f / l_r[r];
    int t = qrow0 + q4 + r;
#pragma unroll
    for (int n = 0; n < 4; n++)
      Y[((long)(b * 1024 + t)) * 1024 + h * 64 + n * 16 + ln15] = f2bf(Oacc[n][r] * inv);
  }
}

// ---------------------------------------------------------------- host
extern "C" void kernel_launch(void* const* d_in, const int* in_sizes, int n_in,
                              void* d_out, int out_size, void* d_ws, size_t ws_size,
                              hipStream_t stream) {
  const float* idx   = (const float*)d_in[0];
  const float* tok_w = (const float*)d_in[1];
  const float* tok_b = (const float*)d_in[2];
  const float* pos   = (const float*)d_in[3];
  const float* ln1g  = (const float*)d_in[4];
  const float* ln1b  = (const float*)d_in[5];
  const float* wq    = (const float*)d_in[6];
  const float* wk    = (const float*)d_in[7];
  const float* wv    = (const float*)d_in[8];
  const float* bq    = (const float*)d_in[9];
  const float* bk    = (const float*)d_in[10];
  const float* bv    = (const float*)d_in[11];
  const float* projw = (const float*)d_in[12];
  const float* projb = (const float*)d_in[13];
  const float* ln2g  = (const float*)d_in[14];
  const float* ln2b  = (const float*)d_in[15];
  const float* ff1w  = (const float*)d_in[16];
  const float* ff1b  = (const float*)d_in[17];
  const float* ff2w  = (const float*)d_in[18];
  const float* ff2b  = (const float*)d_in[19];
  const float* lnfg  = (const float*)d_in[20];
  const float* lnfb  = (const float*)d_in[21];
  const float* headw = (const float*)d_in[22];
  const float* headb = (const float*)d_in[23];

  if (ws_size < 88080384ULL) return;

  char* w = (char*)d_ws;
  unsigned short* idxb   = (unsigned short*)w; w += (long)2048 * 2048 * 2;
  unsigned short* wembT  = (unsigned short*)w; w += (long)1024 * 2048 * 2;
  unsigned short* wheadT = (unsigned short*)w; w += (long)2048 * 1024 * 2;
  unsigned short* wqkvT  = (unsigned short*)w; w += (long)3072 * 1024 * 2;
  unsigned short* wprojT = (unsigned short*)w; w += (long)1024 * 1024 * 2;
  unsigned short* wff1T  = (unsigned short*)w; w += (long)4096 * 1024 * 2;
  unsigned short* wff2T  = (unsigned short*)w; w += (long)1024 * 4096 * 2;
  float*          xbuf   = (float*)w;          w += (long)2048 * 1024 * 4;
  unsigned short* hbuf   = (unsigned short*)w; w += (long)2048 * 1024 * 2;
  unsigned short* qkvb   = (unsigned short*)w; w += (long)2048 * 3072 * 2;
  unsigned short* ybuf   = (unsigned short*)w; w += (long)2048 * 1024 * 2;
  unsigned short* ffb    = (unsigned short*)w; w += (long)2048 * 4096 * 2;

  dim3 b256(256), b32x8(32, 8);

  f2b_kernel<<<2048, b256, 0, stream>>>(idx, idxb, 524288);
  tpack_kernel<<<dim3(32, 64, 1), b32x8, 0, stream>>>(tok_w, wembT, 1024, 2048, 0, 0);
  hipMemsetAsync(xbuf, 0, (long)2048 * 1024 * 4, stream);
  gemm2<<<dim3(16, 16, 4), b256, 0, stream>>>(idxb, wembT, 1024, 2048, 512, 0,
                                              tok_b, nullptr, nullptr, pos, xbuf, nullptr);

  for (int l = 0; l < 8; l++) {
    tpack_kernel<<<dim3(2, 32, 16), b32x8, 0, stream>>>(wq + (long)l * 16 * 65536, wqkvT,
                                                        64, 1024, 65536, 65536);
    tpack_kernel<<<dim3(2, 32, 16), b32x8, 0, stream>>>(wk + (long)l * 16 * 65536, wqkvT + 1024 * 1024,
                                                        64, 1024, 65536, 65536);
    tpack_kernel<<<dim3(2, 32, 16), b32x8, 0, stream>>>(wv + (long)l * 16 * 65536, wqkvT + 2048 * 1024,
                                                        64, 1024, 65536, 65536);
    tpack_kernel<<<dim3(32, 32, 1), b32x8, 0, stream>>>(projw + (long)l * 1048576, wprojT, 1024, 1024, 0, 0);
    tpack_kernel<<<dim3(128, 32, 1), b32x8, 0, stream>>>(ff1w + (long)l * 4194304, wff1T, 4096, 1024, 0, 0);
    tpack_kernel<<<dim3(32, 128, 1), b32x8, 0, stream>>>(ff2w + (long)l * 4194304, wff2T, 1024, 4096, 0, 0);

    ln_kernel<<<2048, b256, 0, stream>>>(xbuf, ln1g + l * 1024, ln1b + l * 1024, hbuf);
    gemm2<<<dim3(48, 16, 1), b256, 0, stream>>>(hbuf, wqkvT, 3072, 1024, 1024, 1,
                                                bq + l * 1024, bk + l * 1024, bv + l * 1024,
                                                nullptr, nullptr, qkvb);
    attn_kernel<<<dim3(16, 32), b256, 0, stream>>>(qkvb, ybuf);
    gemm2<<<dim3(16, 16, 2), b256, 0, stream>>>(ybuf, wprojT, 1024, 1024, 512, 3,
                                                projb + l * 1024, nullptr, nullptr, nullptr, xbuf, nullptr);
    ln_kernel<<<2048, b256, 0, stream>>>(xbuf, ln2g + l * 1024, ln2b + l * 1024, hbuf);
    gemm2<<<dim3(64, 16, 1), b256, 0, stream>>>(hbuf, wff1T, 4096, 1024, 1024, 2,
                                                ff1b + l * 4096, nullptr, nullptr, nullptr, nullptr, ffb);
    gemm2<<<dim3(16, 16, 4), b256, 0, stream>>>(ffb, wff2T, 1024, 4096, 1024, 3,
                                                ff2b + l * 1024, nullptr, nullptr, nullptr, xbuf, nullptr);
  }

  tpack_kernel<<<dim3(64, 32, 1), b32x8, 0, stream>>>(headw, wheadT, 2048, 1024, 0, 0);
  ln_kernel<<<2048, b256, 0, stream>>>(xbuf, lnfg, lnfb, hbuf);
  gemm2<<<dim3(32, 16, 1), b256, 0, stream>>>(hbuf, wheadT, 2048, 1024, 1024, 4,
                                              headb, nullptr, nullptr, nullptr, (float*)d_out, nullptr);
}